// Round 2
// baseline (240.940 us; speedup 1.0000x reference)
//
#include <hip/hip_runtime.h>

#define H 512
#define W 512
#define BB 32
#define CIN 4

// ---------------------------------------------------------------------------
// K1: per input row (b, ci, h): rowSum, first 4 cols, last 4 cols.
// One wave per row; 2 float4 loads/lane; shfl reduce. Writes into d_ws.
// ---------------------------------------------------------------------------
__global__ __launch_bounds__(256) void k_rowagg(
    const float* __restrict__ x, float* __restrict__ rs,
    float4* __restrict__ lft, float4* __restrict__ rgt) {
  const int wv = threadIdx.x >> 6;
  const int lane = threadIdx.x & 63;
  const int row = (blockIdx.x << 2) + wv;  // 0 .. B*CIN*H-1 = 65535
  const float4* p = (const float4*)(x + (size_t)row * W);
  const float4 a = p[lane];
  const float4 b = p[lane + 64];
  float s = (a.x + a.y) + (a.z + a.w) + (b.x + b.y) + (b.z + b.w);
#pragma unroll
  for (int off = 32; off; off >>= 1) s += __shfl_xor(s, off, 64);
  if (lane == 0) {
    rs[row] = s;
    lft[row] = a;          // cols 0..3
  } else if (lane == 63) {
    rgt[row] = b;          // cols 508..511
  }
}

// ---------------------------------------------------------------------------
// K2' (fused): one block per (b,ch,row-chunk). Phase A: recompute m[49] for
// this block's (b,ch) from the row aggregates (identical math to the old
// k_patchmean; 16x redundant but 16x more parallel and overlapped with the
// store stream). Phase B: bilinear upsample of 32 output rows.
// ---------------------------------------------------------------------------
__global__ __launch_bounds__(256) void k_pm_up(
    const float* __restrict__ rs, const float4* __restrict__ lft,
    const float4* __restrict__ rgt, const float* __restrict__ g_w,
    const float* __restrict__ g_b, const float* __restrict__ th_w,
    const float* __restrict__ th_b, float* __restrict__ out) {
  const int bc = blockIdx.x >> 4;     // 0..63  (b*2+ch)
  const int chunk = blockIdx.x & 15;  // 32 output rows per block
  const int b = bc >> 1, ch = bc & 1;
  const int tid = threadIdx.x;

  __shared__ float sw[36];
  __shared__ float sborder[6][7];
  __shared__ float swred[4][7];
  __shared__ float sm[49];
  __shared__ float rv[7][512];

  // ---- Phase A: patch means ------------------------------------------------
  if (tid < 36) {
    const int ci = tid / 9, rem = tid % 9;
    float v = g_w[ch * 36 + tid];
    if (rem == 4) v += th_w[ch * 4 + ci];  // fold 1x1 conv into center tap
    sw[tid] = v;
  }
  __syncthreads();
  float w[4][3][3];
#pragma unroll
  for (int ci = 0; ci < 4; ci++)
#pragma unroll
    for (int dy = 0; dy < 3; dy++)
#pragma unroll
      for (int dx = 0; dx < 3; dx++) w[ci][dy][dx] = sw[ci * 9 + dy * 3 + dx];

  float colTot[7] = {0, 0, 0, 0, 0, 0, 0};
#pragma unroll
  for (int rr2 = 0; rr2 < 2; rr2++) {
    const int r = tid + rr2 * 256;
    float T = 0, fl0 = 0, fl1 = 0, fl2 = 0, fr0 = 0, fr1 = 0, fr2 = 0;
#pragma unroll
    for (int ci = 0; ci < 4; ci++) {
      const int base = (b * CIN + ci) * H;
#pragma unroll
      for (int dyi = 0; dyi < 3; dyi++) {
        const int rrow = r + dyi - 1;
        float rsv = 0.f;
        float4 l4 = make_float4(0.f, 0.f, 0.f, 0.f);
        float4 r4 = make_float4(0.f, 0.f, 0.f, 0.f);
        if (rrow >= 0 && rrow < H) {
          rsv = rs[base + rrow];
          l4 = lft[base + rrow];
          r4 = rgt[base + rrow];
        }
        const float w0 = w[ci][dyi][0], w1 = w[ci][dyi][1], w2 = w[ci][dyi][2];
        // full-row conv total: shifted row sums with boundary corrections
        T += (w0 + w1 + w2) * rsv - w0 * r4.w - w2 * l4.x;
        // conv values at border columns 0,1,2 (zero pad at col -1)
        fl0 += w1 * l4.x + w2 * l4.y;
        fl1 += w0 * l4.x + w1 * l4.y + w2 * l4.z;
        fl2 += w0 * l4.y + w1 * l4.z + w2 * l4.w;
        // conv values at border columns 509,510,511 (zero pad at col 512)
        fr0 += w0 * r4.x + w1 * r4.y + w2 * r4.z;
        fr1 += w0 * r4.y + w1 * r4.z + w2 * r4.w;
        fr2 += w0 * r4.z + w1 * r4.w;
      }
    }
    const float L1 = fl0, L2 = fl0 + fl1, L3 = fl0 + fl1 + fl2;
    const float R1 = fr2, R2 = fr2 + fr1, R3 = fr2 + fr1 + fr0;
    // RS[r][j] = row total minus excluded left/right border columns
    const float RSj[7] = {T - R3, T - R2, T - R1, T, T - L1, T - L2, T - L3};
#pragma unroll
    for (int j = 0; j < 7; j++) colTot[j] += RSj[j];
    if (r < 3) {
#pragma unroll
      for (int j = 0; j < 7; j++) sborder[r][j] = RSj[j];
    } else if (r >= H - 3) {
#pragma unroll
      for (int j = 0; j < 7; j++) sborder[r - (H - 3) + 3][j] = RSj[j];
    }
  }
  const int lane = tid & 63, wv = tid >> 6;
#pragma unroll
  for (int j = 0; j < 7; j++) {
#pragma unroll
    for (int off = 32; off; off >>= 1)
      colTot[j] += __shfl_xor(colTot[j], off, 64);
  }
  if (lane == 0) {
#pragma unroll
    for (int j = 0; j < 7; j++) swred[wv][j] = colTot[j];
  }
  __syncthreads();
  if (tid < 49) {
    const int i = tid / 7, j = tid % 7;
    float s = swred[0][j] + swred[1][j] + swred[2][j] + swred[3][j];
    const int topExcl = (i > 3) ? (i - 3) : 0;  // rows 0..topExcl-1 excluded
    const int botExcl = (i < 3) ? (3 - i) : 0;  // last botExcl rows excluded
    for (int t = 0; t < topExcl; t++) s -= sborder[t][j];
    for (int t = 0; t < botExcl; t++) s -= sborder[5 - t][j];
    const float beff = g_b[ch] + th_b[ch];
    const float cnt = (float)((H - abs(i - 3)) * (W - abs(j - 3)));
    sm[tid] = (s + beff * cnt) * (1.f / ((float)H * (float)W));
  }
  __syncthreads();

  // ---- Phase B: bilinear upsample (half-pixel centers, edge clamp) --------
#pragma unroll
  for (int it = 0; it < 14; it++) {
    const int idx = it * 256 + tid;  // 0..3583
    const int i = idx >> 9;
    const int xx = idx & 511;
    const float sx = (xx + 0.5f) * (7.f / 512.f) - 0.5f;
    const float fx = floorf(sx);
    const float wx = sx - fx;
    const int ix = (int)fx;
    const int ix0 = ix < 0 ? 0 : ix;
    const int ix1 = (ix + 1 > 6) ? 6 : (ix + 1);
    rv[i][xx] = sm[i * 7 + ix0] * (1.f - wx) + sm[i * 7 + ix1] * wx;
  }
  __syncthreads();
  float* ob = out + (size_t)bc * (H * W);
  const int half = tid >> 7;   // 2 rows in flight per iteration
  const int xq = tid & 127;    // float4 index within row
#pragma unroll
  for (int it = 0; it < 16; it++) {
    const int row = chunk * 32 + it * 2 + half;
    const float sy = (row + 0.5f) * (7.f / 512.f) - 0.5f;
    const float fy = floorf(sy);
    const float wy = sy - fy;
    const int iy = (int)fy;
    const int iy0 = iy < 0 ? 0 : iy;
    const int iy1 = (iy + 1 > 6) ? 6 : (iy + 1);
    const float4 a = *(const float4*)&rv[iy0][xq << 2];
    const float4 b4 = *(const float4*)&rv[iy1][xq << 2];
    const float u = 1.f - wy;
    float4 v;
    v.x = a.x * u + b4.x * wy;
    v.y = a.y * u + b4.y * wy;
    v.z = a.z * u + b4.z * wy;
    v.w = a.w * u + b4.w * wy;
    ((float4*)(ob + (size_t)row * W))[xq] = v;
  }
}

extern "C" void kernel_launch(void* const* d_in, const int* in_sizes, int n_in,
                              void* d_out, int out_size, void* d_ws,
                              size_t ws_size, hipStream_t stream) {
  const float* x = (const float*)d_in[0];     // [32,4,512,512]
  const float* g_w = (const float*)d_in[1];   // [2,4,3,3]
  const float* g_b = (const float*)d_in[2];   // [2]
  const float* th_w = (const float*)d_in[3];  // [2,4,1,1]
  const float* th_b = (const float*)d_in[4];  // [2]
  float* out = (float*)d_out;                 // [32,2,512,512]

  // Row aggregates live in d_ws (2.36 MB) so the fused kernel can read them
  // while streaming d_out.
  const int NROWS = BB * CIN * H;                    // 65536
  float* ws = (float*)d_ws;
  float* rs = ws;                                    // [NROWS]
  float4* lft = (float4*)(ws + NROWS);               // [NROWS] cols 0..3
  float4* rgt = (float4*)(ws + NROWS + 4 * NROWS);   // [NROWS] cols 508..511

  k_rowagg<<<NROWS / 4, 256, 0, stream>>>(x, rs, lft, rgt);
  k_pm_up<<<BB * 2 * 16, 256, 0, stream>>>(rs, lft, rgt, g_w, g_b, th_w, th_b,
                                           out);
}

// Round 5
// 216.850 us; speedup vs baseline: 1.1111x; 1.1111x over previous
//
#include <hip/hip_runtime.h>

#define H 512
#define W 512
#define BB 32
#define CIN 4

// Native clang vector type for nontemporal builtins (HIP_vector_type is a
// struct and is rejected by __builtin_nontemporal_*).
typedef float f32x4 __attribute__((ext_vector_type(4)));

// ---------------------------------------------------------------------------
// K1: per input row (b, ci, h): rowSum, first 4 cols, last 4 cols.
// One wave per row; 2 nontemporal 16B loads/lane (x is read-once, keep it
// out of L2); shfl reduce.
// ---------------------------------------------------------------------------
__global__ __launch_bounds__(256) void k_rowagg(
    const float* __restrict__ x, float* __restrict__ rs,
    float4* __restrict__ lft, float4* __restrict__ rgt) {
  const int wv = threadIdx.x >> 6;
  const int lane = threadIdx.x & 63;
  const int row = (blockIdx.x << 2) + wv;  // 0 .. B*CIN*H-1 = 65535
  const f32x4* p = (const f32x4*)(x + (size_t)row * W);
  const f32x4 a = __builtin_nontemporal_load(&p[lane]);
  const f32x4 b = __builtin_nontemporal_load(&p[lane + 64]);
  float s = (a.x + a.y) + (a.z + a.w) + (b.x + b.y) + (b.z + b.w);
#pragma unroll
  for (int off = 32; off; off >>= 1) s += __shfl_xor(s, off, 64);
  if (lane == 0) {
    rs[row] = s;
    lft[row] = make_float4(a.x, a.y, a.z, a.w);   // cols 0..3
  } else if (lane == 63) {
    rgt[row] = make_float4(b.x, b.y, b.z, b.w);   // cols 508..511
  }
}

// ---------------------------------------------------------------------------
// K2: one block per (b, ch). From row aggregates, compute per-row conv totals
// and 7 column-range sums analytically, reduce over rows -> m[b][ch][7][7].
// ---------------------------------------------------------------------------
__global__ __launch_bounds__(256) void k_patchmean(
    const float* __restrict__ rs, const float4* __restrict__ lft,
    const float4* __restrict__ rgt, const float* __restrict__ g_w,
    const float* __restrict__ g_b, const float* __restrict__ th_w,
    const float* __restrict__ th_b, float* __restrict__ mOut) {
  const int bc = blockIdx.x;  // b*2 + ch
  const int b = bc >> 1, ch = bc & 1;
  const int tid = threadIdx.x;
  __shared__ float sw[36];
  __shared__ float sborder[6][7];
  __shared__ float swred[4][7];
  if (tid < 36) {
    const int ci = tid / 9, rem = tid % 9;
    float v = g_w[ch * 36 + tid];
    if (rem == 4) v += th_w[ch * 4 + ci];  // fold 1x1 conv into center tap
    sw[tid] = v;
  }
  __syncthreads();
  float w[4][3][3];
#pragma unroll
  for (int ci = 0; ci < 4; ci++)
#pragma unroll
    for (int dy = 0; dy < 3; dy++)
#pragma unroll
      for (int dx = 0; dx < 3; dx++) w[ci][dy][dx] = sw[ci * 9 + dy * 3 + dx];

  float colTot[7] = {0, 0, 0, 0, 0, 0, 0};
#pragma unroll
  for (int rr2 = 0; rr2 < 2; rr2++) {
    const int r = tid + rr2 * 256;
    float T = 0, fl0 = 0, fl1 = 0, fl2 = 0, fr0 = 0, fr1 = 0, fr2 = 0;
#pragma unroll
    for (int ci = 0; ci < 4; ci++) {
      const int base = (b * CIN + ci) * H;
#pragma unroll
      for (int dyi = 0; dyi < 3; dyi++) {
        const int rrow = r + dyi - 1;
        float rsv = 0.f;
        float4 l4 = make_float4(0.f, 0.f, 0.f, 0.f);
        float4 r4 = make_float4(0.f, 0.f, 0.f, 0.f);
        if (rrow >= 0 && rrow < H) {
          rsv = rs[base + rrow];
          l4 = lft[base + rrow];
          r4 = rgt[base + rrow];
        }
        const float w0 = w[ci][dyi][0], w1 = w[ci][dyi][1], w2 = w[ci][dyi][2];
        // full-row conv total: shifted row sums with boundary corrections
        T += (w0 + w1 + w2) * rsv - w0 * r4.w - w2 * l4.x;
        // conv values at border columns 0,1,2 (zero pad at col -1)
        fl0 += w1 * l4.x + w2 * l4.y;
        fl1 += w0 * l4.x + w1 * l4.y + w2 * l4.z;
        fl2 += w0 * l4.y + w1 * l4.z + w2 * l4.w;
        // conv values at border columns 509,510,511 (zero pad at col 512)
        fr0 += w0 * r4.x + w1 * r4.y + w2 * r4.z;
        fr1 += w0 * r4.y + w1 * r4.z + w2 * r4.w;
        fr2 += w0 * r4.z + w1 * r4.w;
      }
    }
    const float L1 = fl0, L2 = fl0 + fl1, L3 = fl0 + fl1 + fl2;
    const float R1 = fr2, R2 = fr2 + fr1, R3 = fr2 + fr1 + fr0;
    // RS[r][j] = row total minus excluded left/right border columns
    const float RSj[7] = {T - R3, T - R2, T - R1, T, T - L1, T - L2, T - L3};
#pragma unroll
    for (int j = 0; j < 7; j++) colTot[j] += RSj[j];
    if (r < 3) {
#pragma unroll
      for (int j = 0; j < 7; j++) sborder[r][j] = RSj[j];
    } else if (r >= H - 3) {
#pragma unroll
      for (int j = 0; j < 7; j++) sborder[r - (H - 3) + 3][j] = RSj[j];
    }
  }
  const int lane = tid & 63, wv = tid >> 6;
#pragma unroll
  for (int j = 0; j < 7; j++) {
#pragma unroll
    for (int off = 32; off; off >>= 1)
      colTot[j] += __shfl_xor(colTot[j], off, 64);
  }
  if (lane == 0) {
#pragma unroll
    for (int j = 0; j < 7; j++) swred[wv][j] = colTot[j];
  }
  __syncthreads();
  if (tid < 49) {
    const int i = tid / 7, j = tid % 7;
    float s = swred[0][j] + swred[1][j] + swred[2][j] + swred[3][j];
    const int topExcl = (i > 3) ? (i - 3) : 0;  // rows 0..topExcl-1 excluded
    const int botExcl = (i < 3) ? (3 - i) : 0;  // last botExcl rows excluded
    for (int t = 0; t < topExcl; t++) s -= sborder[t][j];
    for (int t = 0; t < botExcl; t++) s -= sborder[5 - t][j];
    const float beff = g_b[ch] + th_b[ch];
    const float cnt = (float)((H - abs(i - 3)) * (W - abs(j - 3)));
    mOut[bc * 49 + tid] = (s + beff * cnt) * (1.f / ((float)H * (float)W));
  }
}

// ---------------------------------------------------------------------------
// K3: bilinear upsample m[64][7][7] -> out[64][512][512], half-pixel centers,
// edge clamp (== jax.image.resize bilinear for upscale). Precompute the 7
// x-interpolated rows in LDS, then each output pixel is a 2-tap y-lerp.
// Nontemporal 16B stores (write-once stream).
// ---------------------------------------------------------------------------
__global__ __launch_bounds__(256) void k_up(const float* __restrict__ m,
                                            float* __restrict__ out) {
  const int bc = blockIdx.x >> 4;     // 0..63  (b*2+ch)
  const int chunk = blockIdx.x & 15;  // 32 rows per block
  const int tid = threadIdx.x;
  __shared__ float sm[49];
  __shared__ float rv[7][512];
  if (tid < 49) sm[tid] = m[bc * 49 + tid];
  __syncthreads();
#pragma unroll
  for (int it = 0; it < 14; it++) {
    const int idx = it * 256 + tid;  // 0..3583
    const int i = idx >> 9;
    const int xx = idx & 511;
    const float sx = (xx + 0.5f) * (7.f / 512.f) - 0.5f;
    const float fx = floorf(sx);
    const float wx = sx - fx;
    const int ix = (int)fx;
    const int ix0 = ix < 0 ? 0 : ix;
    const int ix1 = (ix + 1 > 6) ? 6 : (ix + 1);
    rv[i][xx] = sm[i * 7 + ix0] * (1.f - wx) + sm[i * 7 + ix1] * wx;
  }
  __syncthreads();
  float* ob = out + (size_t)bc * (H * W);
  const int half = tid >> 7;   // 2 rows in flight per iteration
  const int xq = tid & 127;    // float4 index within row
#pragma unroll
  for (int it = 0; it < 16; it++) {
    const int row = chunk * 32 + it * 2 + half;
    const float sy = (row + 0.5f) * (7.f / 512.f) - 0.5f;
    const float fy = floorf(sy);
    const float wy = sy - fy;
    const int iy = (int)fy;
    const int iy0 = iy < 0 ? 0 : iy;
    const int iy1 = (iy + 1 > 6) ? 6 : (iy + 1);
    const float4 a = *(const float4*)&rv[iy0][xq << 2];
    const float4 b4 = *(const float4*)&rv[iy1][xq << 2];
    const float u = 1.f - wy;
    f32x4 v;
    v.x = a.x * u + b4.x * wy;
    v.y = a.y * u + b4.y * wy;
    v.z = a.z * u + b4.z * wy;
    v.w = a.w * u + b4.w * wy;
    __builtin_nontemporal_store(v, &((f32x4*)(ob + (size_t)row * W))[xq]);
  }
}

extern "C" void kernel_launch(void* const* d_in, const int* in_sizes, int n_in,
                              void* d_out, int out_size, void* d_ws,
                              size_t ws_size, hipStream_t stream) {
  const float* x = (const float*)d_in[0];     // [32,4,512,512]
  const float* g_w = (const float*)d_in[1];   // [2,4,3,3]
  const float* g_b = (const float*)d_in[2];   // [2]
  const float* th_w = (const float*)d_in[3];  // [2,4,1,1]
  const float* th_b = (const float*)d_in[4];  // [2]
  float* out = (float*)d_out;                 // [32,2,512,512]

  // Scratch layout (R0 structure — fastest measured): row aggregates live in
  // d_out (overwritten later by K3), tiny m[64][49] lives in d_ws.
  const int NROWS = BB * CIN * H;                       // 65536
  float* rs = out;                                      // [NROWS]
  float4* lft = (float4*)(out + NROWS);                 // [NROWS] cols 0..3
  float4* rgt = (float4*)(out + NROWS + 4 * NROWS);     // [NROWS] cols 508..511
  float* m = (float*)d_ws;                              // 64*49 floats

  k_rowagg<<<NROWS / 4, 256, 0, stream>>>(x, rs, lft, rgt);
  k_patchmean<<<BB * 2, 256, 0, stream>>>(rs, lft, rgt, g_w, g_b, th_w, th_b, m);
  k_up<<<BB * 2 * 16, 256, 0, stream>>>(m, out);
}